// Round 3
// baseline (677.848 us; speedup 1.0000x reference)
//
#include <hip/hip_runtime.h>

#define BB 128
#define CC 768
#define NN 196
#define DD 128
#define KTOP 8

typedef unsigned short u16;
typedef unsigned int u32;

__device__ __forceinline__ u16 f2bfu(float x) {
    u32 i; __builtin_memcpy(&i, &x, 4);
    u32 r = (i + 0x7fffu + ((i >> 16) & 1u)) >> 16;
    return (u16)r;
}
__device__ __forceinline__ void unpack2(u32 u, float& f0, float& f1) {
    u32 lo = u << 16, hi = u & 0xffff0000u;
    __builtin_memcpy(&f0, &lo, 4); __builtin_memcpy(&f1, &hi, 4);
}
__device__ __forceinline__ void unpack8(uint4 u, float* f) {
    unpack2(u.x, f[0], f[1]); unpack2(u.y, f[2], f[3]);
    unpack2(u.z, f[4], f[5]); unpack2(u.w, f[6], f[7]);
}
__device__ __forceinline__ float gelu_f(float x) {
    return 0.5f * x * (1.0f + erff(x * 0.70710678118654752f));
}

// ---------------- Kernel 1: nodes = gelu(LN(feat^T @ Wn + b)) ------------
// grid B*25 (8 n-rows per block, masked), block 128 (one thread per d)
__global__ __launch_bounds__(128)
void node_kernel(const float* __restrict__ feat, const float* __restrict__ Wn,
                 const float* __restrict__ bnode, const float* __restrict__ lng,
                 const float* __restrict__ lnb,
                 float* __restrict__ nodes, float* __restrict__ inv_norm)
{
    __shared__ float xs[CC][8];
    __shared__ float vals[8][DD];
    __shared__ float stats[8][2];
    const int tid = threadIdx.x;
    const int b  = blockIdx.x / 25;
    const int n0 = (blockIdx.x % 25) * 8;
    const float* fb = feat + (size_t)b * CC * NN;
    for (int i = tid; i < CC * 8; i += 128) {
        const int c = i >> 3, nl = i & 7;
        const int n = n0 + nl;
        xs[c][nl] = (n < NN) ? fb[c * NN + n] : 0.0f;
    }
    __syncthreads();
    const int d = tid;
    float acc[8];
#pragma unroll
    for (int r = 0; r < 8; ++r) acc[r] = 0.0f;
    const float* wp = Wn + d;
#pragma unroll 4
    for (int c = 0; c < CC; ++c) {
        const float w = wp[c * DD];
        const float4 x0 = *(const float4*)(&xs[c][0]);
        const float4 x1 = *(const float4*)(&xs[c][4]);
        acc[0] += x0.x * w; acc[1] += x0.y * w; acc[2] += x0.z * w; acc[3] += x0.w * w;
        acc[4] += x1.x * w; acc[5] += x1.y * w; acc[6] += x1.z * w; acc[7] += x1.w * w;
    }
    const float bb = bnode[d];
#pragma unroll
    for (int r = 0; r < 8; ++r) vals[r][d] = acc[r] + bb;
    __syncthreads();
    const int lane = tid & 63, wv = tid >> 6;
    for (int r = wv * 4; r < wv * 4 + 4; ++r) {
        float a0 = vals[r][lane], a1 = vals[r][lane + 64];
        float s = a0 + a1;
#pragma unroll
        for (int off = 32; off > 0; off >>= 1) s += __shfl_xor(s, off);
        const float mu = s * (1.0f / 128.0f);
        float d0 = a0 - mu, d1 = a1 - mu;
        float s2 = d0 * d0 + d1 * d1;
#pragma unroll
        for (int off = 32; off > 0; off >>= 1) s2 += __shfl_xor(s2, off);
        if (lane == 0) { stats[r][0] = mu; stats[r][1] = rsqrtf(s2 * (1.0f/128.0f) + 1e-5f); }
    }
    __syncthreads();
    const float g  = lng[d];
    const float be = lnb[d];
#pragma unroll
    for (int r = 0; r < 8; ++r) {
        const float y = (vals[r][d] - stats[r][0]) * stats[r][1] * g + be;
        acc[r] = gelu_f(y);
    }
    __syncthreads();
#pragma unroll
    for (int r = 0; r < 8; ++r) vals[r][d] = acc[r] * acc[r];
#pragma unroll
    for (int r = 0; r < 8; ++r) {
        const int n = n0 + r;
        if (n < NN) nodes[((size_t)b * NN + n) * DD + d] = acc[r];
    }
    __syncthreads();
    for (int r = wv * 4; r < wv * 4 + 4; ++r) {
        float s = vals[r][lane] + vals[r][lane + 64];
#pragma unroll
        for (int off = 32; off > 0; off >>= 1) s += __shfl_xor(s, off);
        if (lane == 0) {
            const int n = n0 + r;
            if (n < NN) inv_norm[b * NN + n] = 1.0f / fmaxf(sqrtf(s), 1e-12f);
        }
    }
}

// ------------- Kernel 2: S1 = nodes@We1[0:128], N1 = nodes@We1[128:256] --
// grid 392 (64 rows/block), block 256, 8x8 per thread over 64x256 tile
__global__ __launch_bounds__(256)
void s1n1_kernel(const float* __restrict__ nodes, const float* __restrict__ We1,
                 float* __restrict__ S1, float* __restrict__ N1)
{
    __shared__ float atile[64][DD];
    const int tid = threadIdx.x;
    const int row0 = blockIdx.x * 64;
#pragma unroll
    for (int p = 0; p < 8; ++p) {
        const int idx = tid + 256 * p;
        const int r = idx >> 5, q = idx & 31;
        *(float4*)(&atile[r][q * 4]) = *(const float4*)(&nodes[(size_t)(row0 + r) * DD + q * 4]);
    }
    __syncthreads();
    const int rg = tid >> 5;          // 8 row groups of 8
    const int cg = tid & 31;          // 32 col groups of 8 (cols 0..255)
    const int r0 = rg * 8;
    const int c0 = cg * 8;
    const float* wbase = (c0 < DD) ? (We1 + c0) : (We1 + 128 * DD + (c0 - DD));
    float acc[8][8];
#pragma unroll
    for (int i = 0; i < 8; ++i)
#pragma unroll
        for (int j = 0; j < 8; ++j) acc[i][j] = 0.0f;
    for (int k = 0; k < DD; k += 4) {
        float4 av[8];
#pragma unroll
        for (int ri = 0; ri < 8; ++ri) av[ri] = *(const float4*)(&atile[r0 + ri][k]);
#pragma unroll
        for (int kk = 0; kk < 4; ++kk) {
            const float4 w0 = *(const float4*)(wbase + (size_t)(k + kk) * DD);
            const float4 w1 = *(const float4*)(wbase + (size_t)(k + kk) * DD + 4);
            const float wf[8] = {w0.x, w0.y, w0.z, w0.w, w1.x, w1.y, w1.z, w1.w};
#pragma unroll
            for (int ri = 0; ri < 8; ++ri) {
                const float a = (kk == 0) ? av[ri].x : (kk == 1) ? av[ri].y : (kk == 2) ? av[ri].z : av[ri].w;
#pragma unroll
                for (int ci = 0; ci < 8; ++ci) acc[ri][ci] += a * wf[ci];
            }
        }
    }
    float* outp = (c0 < DD) ? (S1 + (size_t)row0 * DD + c0)
                            : (N1 + (size_t)row0 * DD + (c0 - DD));
#pragma unroll
    for (int ri = 0; ri < 8; ++ri) {
        float4 o0 = make_float4(acc[ri][0], acc[ri][1], acc[ri][2], acc[ri][3]);
        float4 o1 = make_float4(acc[ri][4], acc[ri][5], acc[ri][6], acc[ri][7]);
        *(float4*)(outp + (size_t)(r0 + ri) * DD)     = o0;
        *(float4*)(outp + (size_t)(r0 + ri) * DD + 4) = o1;
    }
}

// --------------- Kernel 3: sim = cosine similarity (fp32!) ---------------
// grid B*7 (28 n-rows per block vs all 196 m), block 256, 4x7 per thread
__global__ __launch_bounds__(256)
void sim_kernel(const float* __restrict__ nodes, const float* __restrict__ inv_norm,
                float* __restrict__ sim)
{
    __shared__ float as[28][36];
    __shared__ float bs[NN][36];
    __shared__ float invs[NN];
    const int tid = threadIdx.x;
    const int b  = blockIdx.x / 7;
    const int n0 = (blockIdx.x % 7) * 28;
    const float* nb = nodes + (size_t)b * NN * DD;
    if (tid < NN) invs[tid] = inv_norm[b * NN + tid];
    const bool act = tid < 196;
    const int ai = act ? tid / 28 : 0;
    const int bi = act ? tid % 28 : 0;
    float acc[4][7];
#pragma unroll
    for (int r = 0; r < 4; ++r)
#pragma unroll
        for (int j = 0; j < 7; ++j) acc[r][j] = 0.0f;
    for (int dc = 0; dc < DD; dc += 32) {
        __syncthreads();
        if (tid < 224) {
            const int i = tid >> 3, q = tid & 7;
            *(float4*)(&as[i][q * 4]) = *(const float4*)(&nb[(size_t)(n0 + i) * DD + dc + q * 4]);
        }
        for (int idx = tid; idx < 1568; idx += 256) {
            const int r = idx >> 3, q = idx & 7;
            *(float4*)(&bs[r][q * 4]) = *(const float4*)(&nb[(size_t)r * DD + dc + q * 4]);
        }
        __syncthreads();
        if (act) {
            for (int dd = 0; dd < 32; dd += 4) {
                float4 a4[4], b4[7];
#pragma unroll
                for (int r = 0; r < 4; ++r) a4[r] = *(const float4*)(&as[ai * 4 + r][dd]);
#pragma unroll
                for (int j = 0; j < 7; ++j) b4[j] = *(const float4*)(&bs[bi * 7 + j][dd]);
#pragma unroll
                for (int r = 0; r < 4; ++r)
#pragma unroll
                    for (int j = 0; j < 7; ++j)
                        acc[r][j] += a4[r].x * b4[j].x + a4[r].y * b4[j].y
                                   + a4[r].z * b4[j].z + a4[r].w * b4[j].w;
            }
        }
    }
    if (act) {
#pragma unroll
        for (int r = 0; r < 4; ++r) {
            const int n = n0 + ai * 4 + r;
            const float sn = invs[n];
#pragma unroll
            for (int j = 0; j < 7; ++j) {
                const int m = bi * 7 + j;
                sim[((size_t)b * NN + n) * NN + m] = acc[r][j] * sn * invs[m];
            }
        }
    }
}

// --------------- Kernel 4: top-8 per row (jax tie-break) -----------------
__global__ __launch_bounds__(64)
void topk_kernel(const float* __restrict__ sim, int* __restrict__ adj_i,
                 float* __restrict__ adj_o)
{
    const int bn = blockIdx.x;
    const int n = bn % NN;
    const int lane = threadIdx.x;
    const float* srow = sim + (size_t)bn * NN;
    float v[4]; int mi[4];
#pragma unroll
    for (int s = 0; s < 4; ++s) {
        const int m = lane + 64 * s;
        mi[s] = m;
        v[s] = (m < NN && m != n) ? srow[m] : -3.0e38f;
    }
    for (int r = 0; r < KTOP; ++r) {
        float bv = v[0]; int bm = mi[0];
#pragma unroll
        for (int s = 1; s < 4; ++s) { if (v[s] > bv) { bv = v[s]; bm = mi[s]; } }
#pragma unroll
        for (int off = 32; off > 0; off >>= 1) {
            const float ov = __shfl_xor(bv, off);
            const int   om = __shfl_xor(bm, off);
            if (ov > bv || (ov == bv && om < bm)) { bv = ov; bm = om; }
        }
        if (lane == 0) {
            adj_i[bn * KTOP + r] = bm;
            adj_o[bn * KTOP + r] = (float)bm;
        }
#pragma unroll
        for (int s = 0; s < 4; ++s) if (mi[s] == bm) v[s] = -3.0e38f;
    }
}

// ------- Kernel 5: displacement table PC[729][D] = posmlp(d)@We1[256:384] --
__global__ __launch_bounds__(128)
void pos_kernel(const float* __restrict__ Wp1, const float* __restrict__ bp1,
                const float* __restrict__ Wp2, const float* __restrict__ bp2,
                const float* __restrict__ We1, float* __restrict__ PC)
{
    __shared__ float t1[64];
    __shared__ float sp[DD];
    const int e = blockIdx.x;
    const int dy = e / 27 - 13, dx = e % 27 - 13;
    const float fy = (float)dy / 13.0f, fx = (float)dx / 13.0f;
    const int tid = threadIdx.x;
    if (tid < 64) {
        const float h = fy * Wp1[tid] + fx * Wp1[64 + tid] + bp1[tid];
        t1[tid] = gelu_f(h);
    }
    __syncthreads();
    float s = bp2[tid];
    for (int j = 0; j < 64; ++j) s += t1[j] * Wp2[j * DD + tid];
    sp[tid] = s;
    __syncthreads();
    float o = 0.0f;
    for (int c = 0; c < DD; ++c) o += sp[c] * We1[(size_t)(256 + c) * DD + tid];
    PC[e * DD + tid] = o;
}

// -------- Kernel 6: edges = gelu(S1+N1g+PCg+be1) @ We2 + be2 -------------
// grid B*25 (8 n per block = 64 edge-rows), block 256, 4x8 per thread
__global__ __launch_bounds__(256)
void edge_kernel(const float* __restrict__ S1, const float* __restrict__ N1,
                 const float* __restrict__ PC, const int* __restrict__ adj_i,
                 const float* __restrict__ be1, const float* __restrict__ We2,
                 const float* __restrict__ be2, float* __restrict__ edges_o)
{
    __shared__ u16 ubf[64][136];    // gelu'd edge-input rows, bf16 (pad: 16B-aligned rows)
    __shared__ u16 w2[DD][136];     // We2 bf16, padded
    __shared__ int m_l[64], dx_l[64];
    const int tid = threadIdx.x;
    const int b  = blockIdx.x / 25;
    const int n0 = (blockIdx.x % 25) * 8;
#pragma unroll
    for (int p = 0; p < 16; ++p) {
        const int idx = tid + 256 * p;      // 4096 float4-quads of We2
        const int r = idx >> 5, c4 = (idx & 31) * 4;
        const float4 w = *(const float4*)(&We2[(size_t)r * DD + c4]);
        ushort4 pk;
        pk.x = f2bfu(w.x); pk.y = f2bfu(w.y); pk.z = f2bfu(w.z); pk.w = f2bfu(w.w);
        *(ushort4*)(&w2[r][c4]) = pk;
    }
    if (tid < 64) {
        const int nl = tid >> 3, k = tid & 7;
        const int n = n0 + nl;
        int mm = 0, di = 0;
        if (n < NN) {
            mm = adj_i[((size_t)b * NN + n) * KTOP + k];
            const int iy = n / 14, ix = n % 14;
            const int my = mm / 14, mx = mm % 14;
            di = (my - iy + 13) * 27 + (mx - ix + 13);
        }
        m_l[tid] = mm; dx_l[tid] = di;
    }
    __syncthreads();
#pragma unroll
    for (int p = 0; p < 8; ++p) {
        const int qi = tid + 256 * p;       // 2048 float4-quads
        const int r  = qi >> 5;
        const int dq = (qi & 31) * 4;
        const int n  = n0 + (r >> 3);
        ushort4 pk;
        if (n < NN) {
            const float4 s1 = *(const float4*)(&S1[((size_t)b * NN + n) * DD + dq]);
            const float4 n1 = *(const float4*)(&N1[((size_t)b * NN + m_l[r]) * DD + dq]);
            const float4 pc = *(const float4*)(&PC[(size_t)dx_l[r] * DD + dq]);
            pk.x = f2bfu(gelu_f(s1.x + n1.x + pc.x + be1[dq + 0]));
            pk.y = f2bfu(gelu_f(s1.y + n1.y + pc.y + be1[dq + 1]));
            pk.z = f2bfu(gelu_f(s1.z + n1.z + pc.z + be1[dq + 2]));
            pk.w = f2bfu(gelu_f(s1.w + n1.w + pc.w + be1[dq + 3]));
        } else { pk.x = 0; pk.y = 0; pk.z = 0; pk.w = 0; }
        *(ushort4*)(&ubf[r][dq]) = pk;
    }
    __syncthreads();
    const int rg = tid >> 4, cg = tid & 15;   // 16 row-groups x 16 col-groups
    const int c0 = cg * 8;
    float acc[4][8];
#pragma unroll
    for (int i = 0; i < 4; ++i)
#pragma unroll
        for (int j = 0; j < 8; ++j) acc[i][j] = 0.0f;
    for (int c = 0; c < DD; c += 8) {
        float wf[8][8];
#pragma unroll
        for (int cc = 0; cc < 8; ++cc) {
            const uint4 wu = *(const uint4*)(&w2[c + cc][c0]);
            unpack8(wu, wf[cc]);
        }
#pragma unroll
        for (int ri = 0; ri < 4; ++ri) {
            const int r = rg + 16 * ri;
            const uint4 uu = *(const uint4*)(&ubf[r][c]);
            float uf[8]; unpack8(uu, uf);
#pragma unroll
            for (int cc = 0; cc < 8; ++cc)
#pragma unroll
                for (int ci = 0; ci < 8; ++ci) acc[ri][ci] += uf[cc] * wf[cc][ci];
        }
    }
    float be2f[8];
#pragma unroll
    for (int ci = 0; ci < 8; ++ci) be2f[ci] = be2[c0 + ci];
#pragma unroll
    for (int ri = 0; ri < 4; ++ri) {
        const int r = rg + 16 * ri;
        const int nl = r >> 3, k = r & 7;
        const int n = n0 + nl;
        if (n < NN) {
            float* op = edges_o + (((size_t)b * NN + n) * KTOP + k) * DD + c0;
            float4 o0 = make_float4(acc[ri][0] + be2f[0], acc[ri][1] + be2f[1],
                                    acc[ri][2] + be2f[2], acc[ri][3] + be2f[3]);
            float4 o1 = make_float4(acc[ri][4] + be2f[4], acc[ri][5] + be2f[5],
                                    acc[ri][6] + be2f[6], acc[ri][7] + be2f[7]);
            *(float4*)(op)     = o0;
            *(float4*)(op + 4) = o1;
        }
    }
}

extern "C" void kernel_launch(void* const* d_in, const int* in_sizes, int n_in,
                              void* d_out, int out_size, void* d_ws, size_t ws_size,
                              hipStream_t stream)
{
    const float* feat = (const float*)d_in[0];
    const float* Wn   = (const float*)d_in[1];
    const float* bn   = (const float*)d_in[2];
    const float* lng  = (const float*)d_in[3];
    const float* lnb  = (const float*)d_in[4];
    const float* Wp1  = (const float*)d_in[5];
    const float* bp1  = (const float*)d_in[6];
    const float* Wp2  = (const float*)d_in[7];
    const float* bp2  = (const float*)d_in[8];
    const float* We1  = (const float*)d_in[9];
    const float* be1  = (const float*)d_in[10];
    const float* We2  = (const float*)d_in[11];
    const float* be2  = (const float*)d_in[12];

    float* ws = (float*)d_ws;
    float* sim      = ws;                    //  4,917,248
    float* S1       = ws + 4917248;          //  3,211,264
    float* N1       = ws + 8128512;          //  3,211,264
    float* PC       = ws + 11339776;         //     93,312
    float* inv_norm = ws + 11433088;         //     25,088
    int*   adj_i    = (int*)(ws + 11458176); //    200,704 ints

    float* out      = (float*)d_out;
    float* nodes    = out;                       // [B,N,D]   fp32
    float* edges_o  = out + 3211264;             // [B,N,K,D] fp32
    float* adj_o    = out + 3211264 + 25690112;  // [B,N,K]   fp32 (int values)

    node_kernel<<<BB * 25, 128, 0, stream>>>(feat, Wn, bn, lng, lnb, nodes, inv_norm);
    s1n1_kernel<<<392, 256, 0, stream>>>(nodes, We1, S1, N1);
    pos_kernel<<<729, 128, 0, stream>>>(Wp1, bp1, Wp2, bp2, We1, PC);
    sim_kernel<<<BB * 7, 256, 0, stream>>>(nodes, inv_norm, sim);
    topk_kernel<<<BB * NN, 64, 0, stream>>>(sim, adj_i, adj_o);
    edge_kernel<<<BB * 25, 256, 0, stream>>>(S1, N1, PC, adj_i, be1, We2, be2, edges_o);
}

// Round 4
// 493.036 us; speedup vs baseline: 1.3748x; 1.3748x over previous
//
#include <hip/hip_runtime.h>

#define BB 128
#define CC 768
#define NN 196
#define DD 128
#define KTOP 8
#define MROWS 25088   // B*N

typedef unsigned short u16;
typedef unsigned int u32;

__device__ __forceinline__ u16 f2bfu(float x) {
    u32 i; __builtin_memcpy(&i, &x, 4);
    u32 r = (i + 0x7fffu + ((i >> 16) & 1u)) >> 16;
    return (u16)r;
}
__device__ __forceinline__ void unpack2(u32 u, float& f0, float& f1) {
    u32 lo = u << 16, hi = u & 0xffff0000u;
    __builtin_memcpy(&f0, &lo, 4); __builtin_memcpy(&f1, &hi, 4);
}
__device__ __forceinline__ void unpack8(uint4 u, float* f) {
    unpack2(u.x, f[0], f[1]); unpack2(u.y, f[2], f[3]);
    unpack2(u.z, f[4], f[5]); unpack2(u.w, f[6], f[7]);
}
__device__ __forceinline__ float gelu_f(float x) {
    return 0.5f * x * (1.0f + erff(x * 0.70710678118654752f));
}

// ---------- Kernel 1a: partial[ks][m][d] = feat^T @ Wn (half-K each) -----
// grid (392, 2), block 256. Tile M=64 x N=128, KB=32, 8x4 acc per thread.
__global__ __launch_bounds__(256)
void gemm_node_kernel(const float* __restrict__ feat, const float* __restrict__ Wn,
                      float* __restrict__ part)
{
    __shared__ float As[32][64];    // K-transposed A tile
    __shared__ float Bs[32][DD];
    const int tid = threadIdx.x;
    const int m0  = blockIdx.x * 64;
    const int k0  = blockIdx.y * 384;

    // per-thread A-load coords: r is constant across p (256p % 64 == 0)
    const int r_ld   = tid & 63;
    const int cl_ld  = tid >> 6;         // + 4p
    const int m_ld   = m0 + r_ld;
    const int b_ld   = m_ld / NN;
    const int n_ld   = m_ld % NN;
    const float* fbase = feat + (size_t)b_ld * CC * NN + n_ld;

    const int rg = tid >> 5;             // 8 row-groups of 8 rows
    const int cg = tid & 31;             // 32 col-groups of 4 cols

    float acc[8][4];
#pragma unroll
    for (int i = 0; i < 8; ++i)
#pragma unroll
        for (int j = 0; j < 4; ++j) acc[i][j] = 0.0f;

    for (int kt = 0; kt < 12; ++kt) {
        const int kbase = k0 + kt * 32;
#pragma unroll
        for (int p = 0; p < 8; ++p) {
            const int cl = cl_ld + 4 * p;
            As[cl][r_ld] = fbase[(size_t)(kbase + cl) * NN];
        }
#pragma unroll
        for (int p = 0; p < 4; ++p) {
            const int q = tid + 256 * p;
            const int cl = q >> 5, d4 = (q & 31) * 4;
            *(float4*)(&Bs[cl][d4]) = *(const float4*)(&Wn[(size_t)(kbase + cl) * DD + d4]);
        }
        __syncthreads();
#pragma unroll
        for (int kk = 0; kk < 32; ++kk) {
            const float4 a0 = *(const float4*)(&As[kk][rg * 8]);
            const float4 a1 = *(const float4*)(&As[kk][rg * 8 + 4]);
            const float4 bv = *(const float4*)(&Bs[kk][cg * 4]);
            const float af[8] = {a0.x, a0.y, a0.z, a0.w, a1.x, a1.y, a1.z, a1.w};
#pragma unroll
            for (int i = 0; i < 8; ++i) {
                acc[i][0] += af[i] * bv.x; acc[i][1] += af[i] * bv.y;
                acc[i][2] += af[i] * bv.z; acc[i][3] += af[i] * bv.w;
            }
        }
        __syncthreads();
    }
    float* op = part + ((size_t)blockIdx.y * MROWS + m0 + rg * 8) * DD + cg * 4;
#pragma unroll
    for (int i = 0; i < 8; ++i) {
        *(float4*)(op + (size_t)i * DD) =
            make_float4(acc[i][0], acc[i][1], acc[i][2], acc[i][3]);
    }
}

// ---------- Kernel 1b: nodes = gelu(LN(part0+part1+b)), + inv_norm -------
// grid 3136 (8 rows/block), block 128 (one thread per d)
__global__ __launch_bounds__(128)
void ln_kernel(const float* __restrict__ part, const float* __restrict__ bnode,
               const float* __restrict__ lng, const float* __restrict__ lnb,
               float* __restrict__ nodes, float* __restrict__ inv_norm)
{
    __shared__ float vals[8][DD];
    __shared__ float stats[8][2];
    const int tid = threadIdx.x;
    const int row0 = blockIdx.x * 8;
    const int d = tid;
    const float bb = bnode[d];
#pragma unroll
    for (int r = 0; r < 8; ++r) {
        const size_t m = row0 + r;
        vals[r][d] = part[m * DD + d] + part[(size_t)(MROWS + m) * DD + d] + bb;
    }
    __syncthreads();
    const int lane = tid & 63, wv = tid >> 6;
    for (int r = wv * 4; r < wv * 4 + 4; ++r) {
        float a0 = vals[r][lane], a1 = vals[r][lane + 64];
        float s = a0 + a1;
#pragma unroll
        for (int off = 32; off > 0; off >>= 1) s += __shfl_xor(s, off);
        const float mu = s * (1.0f / 128.0f);
        float d0 = a0 - mu, d1 = a1 - mu;
        float s2 = d0 * d0 + d1 * d1;
#pragma unroll
        for (int off = 32; off > 0; off >>= 1) s2 += __shfl_xor(s2, off);
        if (lane == 0) { stats[r][0] = mu; stats[r][1] = rsqrtf(s2 * (1.0f/128.0f) + 1e-5f); }
    }
    __syncthreads();
    const float g  = lng[d];
    const float be = lnb[d];
    float acc[8];
#pragma unroll
    for (int r = 0; r < 8; ++r) {
        const float y = (vals[r][d] - stats[r][0]) * stats[r][1] * g + be;
        acc[r] = gelu_f(y);
    }
    __syncthreads();
#pragma unroll
    for (int r = 0; r < 8; ++r) vals[r][d] = acc[r] * acc[r];
#pragma unroll
    for (int r = 0; r < 8; ++r) nodes[(size_t)(row0 + r) * DD + d] = acc[r];
    __syncthreads();
    for (int r = wv * 4; r < wv * 4 + 4; ++r) {
        float s = vals[r][lane] + vals[r][lane + 64];
#pragma unroll
        for (int off = 32; off > 0; off >>= 1) s += __shfl_xor(s, off);
        if (lane == 0) inv_norm[row0 + r] = 1.0f / fmaxf(sqrtf(s), 1e-12f);
    }
}

// ------------- Kernel 2: S1 = nodes@We1[0:128], N1 = nodes@We1[128:256] --
__global__ __launch_bounds__(256)
void s1n1_kernel(const float* __restrict__ nodes, const float* __restrict__ We1,
                 float* __restrict__ S1, float* __restrict__ N1)
{
    __shared__ float atile[64][DD];
    const int tid = threadIdx.x;
    const int row0 = blockIdx.x * 64;
#pragma unroll
    for (int p = 0; p < 8; ++p) {
        const int idx = tid + 256 * p;
        const int r = idx >> 5, q = idx & 31;
        *(float4*)(&atile[r][q * 4]) = *(const float4*)(&nodes[(size_t)(row0 + r) * DD + q * 4]);
    }
    __syncthreads();
    const int rg = tid >> 5;
    const int cg = tid & 31;
    const int r0 = rg * 8;
    const int c0 = cg * 8;
    const float* wbase = (c0 < DD) ? (We1 + c0) : (We1 + 128 * DD + (c0 - DD));
    float acc[8][8];
#pragma unroll
    for (int i = 0; i < 8; ++i)
#pragma unroll
        for (int j = 0; j < 8; ++j) acc[i][j] = 0.0f;
    for (int k = 0; k < DD; k += 4) {
        float4 av[8];
#pragma unroll
        for (int ri = 0; ri < 8; ++ri) av[ri] = *(const float4*)(&atile[r0 + ri][k]);
#pragma unroll
        for (int kk = 0; kk < 4; ++kk) {
            const float4 w0 = *(const float4*)(wbase + (size_t)(k + kk) * DD);
            const float4 w1 = *(const float4*)(wbase + (size_t)(k + kk) * DD + 4);
            const float wf[8] = {w0.x, w0.y, w0.z, w0.w, w1.x, w1.y, w1.z, w1.w};
#pragma unroll
            for (int ri = 0; ri < 8; ++ri) {
                const float a = (kk == 0) ? av[ri].x : (kk == 1) ? av[ri].y : (kk == 2) ? av[ri].z : av[ri].w;
#pragma unroll
                for (int ci = 0; ci < 8; ++ci) acc[ri][ci] += a * wf[ci];
            }
        }
    }
    float* outp = (c0 < DD) ? (S1 + (size_t)row0 * DD + c0)
                            : (N1 + (size_t)row0 * DD + (c0 - DD));
#pragma unroll
    for (int ri = 0; ri < 8; ++ri) {
        *(float4*)(outp + (size_t)(r0 + ri) * DD) =
            make_float4(acc[ri][0], acc[ri][1], acc[ri][2], acc[ri][3]);
        *(float4*)(outp + (size_t)(r0 + ri) * DD + 4) =
            make_float4(acc[ri][4], acc[ri][5], acc[ri][6], acc[ri][7]);
    }
}

// --------------- Kernel 3: sim = cosine similarity (fp32!) ---------------
__global__ __launch_bounds__(256)
void sim_kernel(const float* __restrict__ nodes, const float* __restrict__ inv_norm,
                float* __restrict__ sim)
{
    __shared__ float as[28][36];
    __shared__ float bs[NN][36];
    __shared__ float invs[NN];
    const int tid = threadIdx.x;
    const int b  = blockIdx.x / 7;
    const int n0 = (blockIdx.x % 7) * 28;
    const float* nb = nodes + (size_t)b * NN * DD;
    if (tid < NN) invs[tid] = inv_norm[b * NN + tid];
    const bool act = tid < 196;
    const int ai = act ? tid / 28 : 0;
    const int bi = act ? tid % 28 : 0;
    float acc[4][7];
#pragma unroll
    for (int r = 0; r < 4; ++r)
#pragma unroll
        for (int j = 0; j < 7; ++j) acc[r][j] = 0.0f;
    for (int dc = 0; dc < DD; dc += 32) {
        __syncthreads();
        if (tid < 224) {
            const int i = tid >> 3, q = tid & 7;
            *(float4*)(&as[i][q * 4]) = *(const float4*)(&nb[(size_t)(n0 + i) * DD + dc + q * 4]);
        }
        for (int idx = tid; idx < 1568; idx += 256) {
            const int r = idx >> 3, q = idx & 7;
            *(float4*)(&bs[r][q * 4]) = *(const float4*)(&nb[(size_t)r * DD + dc + q * 4]);
        }
        __syncthreads();
        if (act) {
            for (int dd = 0; dd < 32; dd += 4) {
                float4 a4[4], b4[7];
#pragma unroll
                for (int r = 0; r < 4; ++r) a4[r] = *(const float4*)(&as[ai * 4 + r][dd]);
#pragma unroll
                for (int j = 0; j < 7; ++j) b4[j] = *(const float4*)(&bs[bi * 7 + j][dd]);
#pragma unroll
                for (int r = 0; r < 4; ++r)
#pragma unroll
                    for (int j = 0; j < 7; ++j)
                        acc[r][j] += a4[r].x * b4[j].x + a4[r].y * b4[j].y
                                   + a4[r].z * b4[j].z + a4[r].w * b4[j].w;
            }
        }
    }
    if (act) {
#pragma unroll
        for (int r = 0; r < 4; ++r) {
            const int n = n0 + ai * 4 + r;
            const float sn = invs[n];
#pragma unroll
            for (int j = 0; j < 7; ++j) {
                const int m = bi * 7 + j;
                sim[((size_t)b * NN + n) * NN + m] = acc[r][j] * sn * invs[m];
            }
        }
    }
}

// --------------- Kernel 4: top-8 per row (jax tie-break) -----------------
__global__ __launch_bounds__(64)
void topk_kernel(const float* __restrict__ sim, int* __restrict__ adj_i,
                 float* __restrict__ adj_o)
{
    const int bn = blockIdx.x;
    const int n = bn % NN;
    const int lane = threadIdx.x;
    const float* srow = sim + (size_t)bn * NN;
    float v[4]; int mi[4];
#pragma unroll
    for (int s = 0; s < 4; ++s) {
        const int m = lane + 64 * s;
        mi[s] = m;
        v[s] = (m < NN && m != n) ? srow[m] : -3.0e38f;
    }
    for (int r = 0; r < KTOP; ++r) {
        float bv = v[0]; int bm = mi[0];
#pragma unroll
        for (int s = 1; s < 4; ++s) { if (v[s] > bv) { bv = v[s]; bm = mi[s]; } }
#pragma unroll
        for (int off = 32; off > 0; off >>= 1) {
            const float ov = __shfl_xor(bv, off);
            const int   om = __shfl_xor(bm, off);
            if (ov > bv || (ov == bv && om < bm)) { bv = ov; bm = om; }
        }
        if (lane == 0) {
            adj_i[bn * KTOP + r] = bm;
            adj_o[bn * KTOP + r] = (float)bm;
        }
#pragma unroll
        for (int s = 0; s < 4; ++s) if (mi[s] == bm) v[s] = -3.0e38f;
    }
}

// ------- Kernel 5: displacement table PC[729][D] = posmlp(d)@We1[256:384] --
__global__ __launch_bounds__(128)
void pos_kernel(const float* __restrict__ Wp1, const float* __restrict__ bp1,
                const float* __restrict__ Wp2, const float* __restrict__ bp2,
                const float* __restrict__ We1, float* __restrict__ PC)
{
    __shared__ float t1[64];
    __shared__ float sp[DD];
    const int e = blockIdx.x;
    const int dy = e / 27 - 13, dx = e % 27 - 13;
    const float fy = (float)dy / 13.0f, fx = (float)dx / 13.0f;
    const int tid = threadIdx.x;
    if (tid < 64) {
        const float h = fy * Wp1[tid] + fx * Wp1[64 + tid] + bp1[tid];
        t1[tid] = gelu_f(h);
    }
    __syncthreads();
    float s = bp2[tid];
    for (int j = 0; j < 64; ++j) s += t1[j] * Wp2[j * DD + tid];
    sp[tid] = s;
    __syncthreads();
    float o = 0.0f;
    for (int c = 0; c < DD; ++c) o += sp[c] * We1[(size_t)(256 + c) * DD + tid];
    PC[e * DD + tid] = o;
}

// -------- Kernel 6: edges = gelu(S1+N1g+PCg+be1) @ We2 + be2 -------------
__global__ __launch_bounds__(256)
void edge_kernel(const float* __restrict__ S1, const float* __restrict__ N1,
                 const float* __restrict__ PC, const int* __restrict__ adj_i,
                 const float* __restrict__ be1, const float* __restrict__ We2,
                 const float* __restrict__ be2, float* __restrict__ edges_o)
{
    __shared__ u16 ubf[64][136];
    __shared__ u16 w2[DD][136];
    __shared__ int m_l[64], dx_l[64];
    const int tid = threadIdx.x;
    const int b  = blockIdx.x / 25;
    const int n0 = (blockIdx.x % 25) * 8;
#pragma unroll
    for (int p = 0; p < 16; ++p) {
        const int idx = tid + 256 * p;
        const int r = idx >> 5, c4 = (idx & 31) * 4;
        const float4 w = *(const float4*)(&We2[(size_t)r * DD + c4]);
        ushort4 pk;
        pk.x = f2bfu(w.x); pk.y = f2bfu(w.y); pk.z = f2bfu(w.z); pk.w = f2bfu(w.w);
        *(ushort4*)(&w2[r][c4]) = pk;
    }
    if (tid < 64) {
        const int nl = tid >> 3, k = tid & 7;
        const int n = n0 + nl;
        int mm = 0, di = 0;
        if (n < NN) {
            mm = adj_i[((size_t)b * NN + n) * KTOP + k];
            const int iy = n / 14, ix = n % 14;
            const int my = mm / 14, mx = mm % 14;
            di = (my - iy + 13) * 27 + (mx - ix + 13);
        }
        m_l[tid] = mm; dx_l[tid] = di;
    }
    __syncthreads();
#pragma unroll
    for (int p = 0; p < 8; ++p) {
        const int qi = tid + 256 * p;
        const int r  = qi >> 5;
        const int dq = (qi & 31) * 4;
        const int n  = n0 + (r >> 3);
        ushort4 pk;
        if (n < NN) {
            const float4 s1 = *(const float4*)(&S1[((size_t)b * NN + n) * DD + dq]);
            const float4 n1 = *(const float4*)(&N1[((size_t)b * NN + m_l[r]) * DD + dq]);
            const float4 pc = *(const float4*)(&PC[(size_t)dx_l[r] * DD + dq]);
            pk.x = f2bfu(gelu_f(s1.x + n1.x + pc.x + be1[dq + 0]));
            pk.y = f2bfu(gelu_f(s1.y + n1.y + pc.y + be1[dq + 1]));
            pk.z = f2bfu(gelu_f(s1.z + n1.z + pc.z + be1[dq + 2]));
            pk.w = f2bfu(gelu_f(s1.w + n1.w + pc.w + be1[dq + 3]));
        } else { pk.x = 0; pk.y = 0; pk.z = 0; pk.w = 0; }
        *(ushort4*)(&ubf[r][dq]) = pk;
    }
    __syncthreads();
    const int rg = tid >> 4, cg = tid & 15;
    const int c0 = cg * 8;
    float acc[4][8];
#pragma unroll
    for (int i = 0; i < 4; ++i)
#pragma unroll
        for (int j = 0; j < 8; ++j) acc[i][j] = 0.0f;
    for (int c = 0; c < DD; c += 8) {
        float wf[8][8];
#pragma unroll
        for (int cc = 0; cc < 8; ++cc) {
            const uint4 wu = *(const uint4*)(&w2[c + cc][c0]);
            unpack8(wu, wf[cc]);
        }
#pragma unroll
        for (int ri = 0; ri < 4; ++ri) {
            const int r = rg + 16 * ri;
            const uint4 uu = *(const uint4*)(&ubf[r][c]);
            float uf[8]; unpack8(uu, uf);
#pragma unroll
            for (int cc = 0; cc < 8; ++cc)
#pragma unroll
                for (int ci = 0; ci < 8; ++ci) acc[ri][ci] += uf[cc] * wf[cc][ci];
        }
    }
    float be2f[8];
#pragma unroll
    for (int ci = 0; ci < 8; ++ci) be2f[ci] = be2[c0 + ci];
#pragma unroll
    for (int ri = 0; ri < 4; ++ri) {
        const int r = rg + 16 * ri;
        const int nl = r >> 3, k = r & 7;
        const int n = n0 + nl;
        if (n < NN) {
            float* op = edges_o + (((size_t)b * NN + n) * KTOP + k) * DD + c0;
            *(float4*)(op)     = make_float4(acc[ri][0] + be2f[0], acc[ri][1] + be2f[1],
                                             acc[ri][2] + be2f[2], acc[ri][3] + be2f[3]);
            *(float4*)(op + 4) = make_float4(acc[ri][4] + be2f[4], acc[ri][5] + be2f[5],
                                             acc[ri][6] + be2f[6], acc[ri][7] + be2f[7]);
        }
    }
}

extern "C" void kernel_launch(void* const* d_in, const int* in_sizes, int n_in,
                              void* d_out, int out_size, void* d_ws, size_t ws_size,
                              hipStream_t stream)
{
    const float* feat = (const float*)d_in[0];
    const float* Wn   = (const float*)d_in[1];
    const float* bn   = (const float*)d_in[2];
    const float* lng  = (const float*)d_in[3];
    const float* lnb  = (const float*)d_in[4];
    const float* Wp1  = (const float*)d_in[5];
    const float* bp1  = (const float*)d_in[6];
    const float* Wp2  = (const float*)d_in[7];
    const float* bp2  = (const float*)d_in[8];
    const float* We1  = (const float*)d_in[9];
    const float* be1  = (const float*)d_in[10];
    const float* We2  = (const float*)d_in[11];
    const float* be2  = (const float*)d_in[12];

    float* ws = (float*)d_ws;
    // part (6,422,528 floats) aliases [sim | head of S1] — dead before s1n1/sim run
    float* part     = ws;                    //  0 .. 6,422,528
    float* sim      = ws;                    //  4,917,248
    float* S1       = ws + 4917248;          //  3,211,264
    float* N1       = ws + 8128512;          //  3,211,264
    float* PC       = ws + 11339776;         //     93,312
    float* inv_norm = ws + 11433088;         //     25,088
    int*   adj_i    = (int*)(ws + 11458176); //    200,704 ints

    float* out      = (float*)d_out;
    float* nodes    = out;                       // [B,N,D]   fp32
    float* edges_o  = out + 3211264;             // [B,N,K,D] fp32
    float* adj_o    = out + 3211264 + 25690112;  // [B,N,K]   fp32 (int values)

    gemm_node_kernel<<<dim3(392, 2), 256, 0, stream>>>(feat, Wn, part);
    ln_kernel<<<3136, 128, 0, stream>>>(part, bn, lng, lnb, nodes, inv_norm);
    s1n1_kernel<<<392, 256, 0, stream>>>(nodes, We1, S1, N1);
    pos_kernel<<<729, 128, 0, stream>>>(Wp1, bp1, Wp2, bp2, We1, PC);
    sim_kernel<<<BB * 7, 256, 0, stream>>>(nodes, inv_norm, sim);
    topk_kernel<<<BB * NN, 64, 0, stream>>>(sim, adj_i, adj_o);
    edge_kernel<<<BB * 25, 256, 0, stream>>>(S1, N1, PC, adj_i, be1, We2, be2, edges_o);
}